// Round 11
// baseline (483.918 us; speedup 1.0000x reference)
//
#include <hip/hip_runtime.h>

#define T_STEPS 128
#define B_SIZE  32768
#define F_DIM   8
#define H_DIM   64

#define BLOCK_THREADS 256                 // 4 waves; wave q owns h-units [16q,16q+16)
#define GRID_BLOCKS   (B_SIZE / 32)       // 1024 blocks x 2 groups of 16 samples

typedef float f32x4 __attribute__((ext_vector_type(4)));
typedef short bfrag __attribute__((ext_vector_type(8)));   // 8 bf16 (4 VGPRs)
typedef short s16x4 __attribute__((ext_vector_type(4)));
typedef unsigned int u32x2 __attribute__((ext_vector_type(2)));
typedef unsigned int u32x4 __attribute__((ext_vector_type(4)));

#define MFMA16(A, B, C) __builtin_amdgcn_mfma_f32_16x16x32_bf16((A), (B), (C), 0, 0, 0)

// Barrier that drains ONLY LDS ops: keeps x-prefetch global loads in flight
// across the per-step exchange (__syncthreads drains vmcnt(0) and puts L2/L3
// latency on every step's critical path). Numerics validated in R9.
#define LDS_BARRIER() asm volatile("s_waitcnt lgkmcnt(0)\n\ts_barrier" ::: "memory")

__device__ __forceinline__ short f2bf(float f) { return __builtin_bit_cast(short, (__bf16)f); }
__device__ __forceinline__ float4 ld4(const void* p) { return *(const float4*)p; }

constexpr float S1 = 1.4426950408889634f;  // log2(e)   -> folded into r,z weights
constexpr float S2 = 2.f * S1;             // 2*log2(e) -> folded into n weights

// Layout (verified rounds 2-10):
//  A/B frag elem e -> k = 32*kt + 16*(e>>2) + 4*g + (e&3); A row / B col = lane&15
//  C/D: col = lane&15 (sample), row = 4*g + reg
// 4-way h-split: wave q owns rows [16q,16q+16); its hc[r4] packs into hB frag
// kt=q>>1 half hq=q&1. Two independent 16-sample groups share weight registers.
// Cap law (R2-R10): VGPR cap = 256/launch_bounds_w; w=2 -> 128 >= demand.

__global__ void __launch_bounds__(BLOCK_THREADS, 2)
seq2seq_r11_kernel(const float* __restrict__ inputs, const float* __restrict__ target,
                   const float* __restrict__ eWih, const float* __restrict__ eWhh,
                   const float* __restrict__ ebih, const float* __restrict__ ebhh,
                   const float* __restrict__ dWih, const float* __restrict__ dWhh,
                   const float* __restrict__ dbih, const float* __restrict__ dbhh,
                   const float* __restrict__ oW, const float* __restrict__ ob,
                   float* __restrict__ out)
{
    __shared__ u32x2 sEx[2][2][2][64][2];   // [parity][grp][kt][lane][half] = 8 KB
    __shared__ u32x4 sWo[2][64];            // out-proj A-frags [kt][lane]     = 2 KB

    const int tid  = threadIdx.x;
    const int lane = tid & 63;
    const int q    = tid >> 6;        // wave id = owned row-tile
    const int c    = lane & 15;       // sample col / A row
    const int g    = lane >> 4;       // lane group
    const int kq   = q >> 1;          // own frag kt
    const int hq   = q & 1;           // own half within frag

    bfrag wr[2], wz[2], whn[2];       // h-side A-frags for own 16 rows, [kt]
    bfrag xr, xz, xnw;                // x-ktile A-frags (k<8 = Wih, k==8 = bias row)
    f32x4 bhn;                        // bhh n-rows (scaled) -> acc-init for aHN

    auto load_phase = [&](const float* __restrict__ Wih, const float* __restrict__ Whh,
                          const float* __restrict__ bih, const float* __restrict__ bhh) {
        const int rowR = 16 * q + c, rowZ = rowR + 64, rowN = rowR + 128;
#pragma unroll
        for (int kt = 0; kt < 2; ++kt) {
            bfrag fr, fz, fn;
#pragma unroll
            for (int e = 0; e < 8; ++e) {
                const int k = 32 * kt + 16 * (e >> 2) + 4 * g + (e & 3);
                fr[e] = f2bf(Whh[rowR * H_DIM + k] * S1);
                fz[e] = f2bf(Whh[rowZ * H_DIM + k] * S1);
                fn[e] = f2bf(Whh[rowN * H_DIM + k] * S2);
            }
            wr[kt] = fr; wz[kt] = fz; whn[kt] = fn;
        }
#pragma unroll
        for (int e = 0; e < 8; ++e) {
            const int k = 16 * (e >> 2) + 4 * g + (e & 3);
            float vr = 0.f, vz = 0.f, vn = 0.f;
            if (k < F_DIM) {
                vr = Wih[rowR * F_DIM + k]; vz = Wih[rowZ * F_DIM + k]; vn = Wih[rowN * F_DIM + k];
            } else if (k == F_DIM) {
                vr = bih[rowR] + bhh[rowR]; vz = bih[rowZ] + bhh[rowZ]; vn = bih[rowN];
            }
            xr[e] = f2bf(vr * S1); xz[e] = f2bf(vz * S1); xnw[e] = f2bf(vn * S2);
        }
#pragma unroll
        for (int r4 = 0; r4 < 4; ++r4) bhn[r4] = bhh[128 + 16 * q + 4 * g + r4] * S2;
    };

    f32x4 hc[2] = {{0.f,0.f,0.f,0.f},{0.f,0.f,0.f,0.f}};                 // [grp]
    bfrag hB[2][2] = {{(bfrag){0,0,0,0,0,0,0,0},(bfrag){0,0,0,0,0,0,0,0}},
                      {(bfrag){0,0,0,0,0,0,0,0},(bfrag){0,0,0,0,0,0,0,0}}};  // [grp][kt]
    bfrag bx0 = (bfrag){0,0,0,0,0,0,0,0};    // ones row at k==8 -> g==2, e==0
    if (g == 2) bx0[0] = f2bf(1.f);

    auto make_bx = [&](const float4 xv) {
        bfrag bx = bx0;
        if (g < 2) { bx[0] = f2bf(xv.x); bx[1] = f2bf(xv.y); bx[2] = f2bf(xv.z); bx[3] = f2bf(xv.w); }
        return bx;
    };

    // One group's GRU step: 9 MFMAs + epilogue; returns packed own 8B of h_new.
    auto step = [&](const bfrag bx, const bfrag hB0, const bfrag hB1, f32x4& HC) -> u32x2 {
        __builtin_amdgcn_s_setprio(1);
        f32x4 aIN = {0.f,0.f,0.f,0.f};
        aIN = MFMA16(xnw, bx, aIN);
        f32x4 aR = {0.f,0.f,0.f,0.f};
        aR = MFMA16(xr, bx, aR);
        aR = MFMA16(wr[0], hB0, aR);
        aR = MFMA16(wr[1], hB1, aR);
        f32x4 aZ = {0.f,0.f,0.f,0.f};
        aZ = MFMA16(xz, bx, aZ);
        aZ = MFMA16(wz[0], hB0, aZ);
        aZ = MFMA16(wz[1], hB1, aZ);
        f32x4 aHN = bhn;                          // bias via acc-init
        aHN = MFMA16(whn[0], hB0, aHN);
        aHN = MFMA16(whn[1], hB1, aHN);
        __builtin_amdgcn_s_setprio(0);
        s16x4 nb;
#pragma unroll
        for (int r4 = 0; r4 < 4; ++r4) {
            // pre-activations arrive pre-scaled by log2e (r,z) / 2log2e (n)
            const float rg = __builtin_amdgcn_rcpf(1.f + __builtin_amdgcn_exp2f(-aR[r4]));
            const float zg = __builtin_amdgcn_rcpf(1.f + __builtin_amdgcn_exp2f(-aZ[r4]));
            const float np = aIN[r4] + rg * aHN[r4];
            const float ng = 1.f - 2.f * __builtin_amdgcn_rcpf(__builtin_amdgcn_exp2f(np) + 1.f);
            HC[r4] = ng + zg * (HC[r4] - ng);
            nb[r4] = f2bf(HC[r4]);
        }
        return __builtin_bit_cast(u32x2, nb);
    };

    const unsigned istep = B_SIZE * F_DIM * 4;
    const unsigned imax  = (T_STEPS - 1) * istep;   // clamp for encoder prefetch
    const unsigned offg[2] = {
        ((unsigned)(blockIdx.x * 32 + c) * F_DIM + 4 * g) * 4u,
        ((unsigned)(blockIdx.x * 32 + 16 + c) * F_DIM + 4 * g) * 4u };

    // ================= encoder =================
    load_phase(eWih, eWhh, ebih, ebhh);
    __syncthreads();
    float4 xn[2] = {make_float4(0.f,0.f,0.f,0.f), make_float4(0.f,0.f,0.f,0.f)};
    if (g < 2) { xn[0] = ld4((const char*)inputs + offg[0]); xn[1] = ld4((const char*)inputs + offg[1]); }
    unsigned ioff = istep;

    auto enc_body = [&](const int P) {   // P = compile-time parity slot
#pragma unroll
        for (int grp = 0; grp < 2; ++grp) {
            const float4 xv = xn[grp];
            if (g < 2) xn[grp] = ld4((const char*)inputs + ioff + offg[grp]);  // in flight across barrier
            const u32x2 nl = step(make_bx(xv), hB[grp][0], hB[grp][1], hc[grp]);
            sEx[P][grp][kq][lane][hq] = nl;
        }
        // branchless uniform clamp (last step re-reads slab 127; harmless)
        const unsigned nxt = ioff + istep;
        ioff = (nxt <= imax) ? nxt : imax;
        LDS_BARRIER();                            // all 8 half-frags written
#pragma unroll
        for (int grp = 0; grp < 2; ++grp) {
            hB[grp][0] = __builtin_bit_cast(bfrag, *(const u32x4*)&sEx[P][grp][0][lane][0]);
            hB[grp][1] = __builtin_bit_cast(bfrag, *(const u32x4*)&sEx[P][grp][1][lane][0]);
        }
    };
#pragma unroll 1
    for (int t = 0; t < T_STEPS; t += 2) {
        enc_body(0);
        enc_body(1);
    }

    // ================= decoder =================
    __syncthreads();   // encoder sEx readers done (also drains prefetch)
    load_phase(dWih, dWhh, dbih, dbhh);
    if (q < 2) {       // wave q writes out-proj frag kt=q to LDS
        bfrag bf_;
#pragma unroll
        for (int e = 0; e < 8; ++e) {
            const int k = 32 * q + 16 * (e >> 2) + 4 * g + (e & 3);
            bf_[e] = f2bf((c < F_DIM) ? oW[c * H_DIM + k] : 0.f);
        }
        sWo[q][lane] = __builtin_bit_cast(u32x4, bf_);
    }
    f32x4 obv;
#pragma unroll
    for (int r4 = 0; r4 < 4; ++r4) obv[r4] = (g < 2) ? ob[4 * g + r4] : 0.f;
    __syncthreads();

    unsigned toff = 0;              // target[t] feeds x_{t+1}; t=127 load unused but in-bounds
    unsigned ooff = 0;
    xn[0] = xn[1] = make_float4(0.f, 0.f, 0.f, 0.f);   // teacher forcing: x_0 = 0

    auto dec_body = [&](const int P, const int t) {
#pragma unroll
        for (int grp = 0; grp < 2; ++grp) {
            const float4 xv = xn[grp];
            if (g < 2) xn[grp] = ld4((const char*)target + toff + offg[grp]);
            const u32x2 nl = step(make_bx(xv), hB[grp][0], hB[grp][1], hc[grp]);
            sEx[P][grp][kq][lane][hq] = nl;
        }
        toff += istep;
        LDS_BARRIER();
#pragma unroll
        for (int grp = 0; grp < 2; ++grp) {
            hB[grp][0] = __builtin_bit_cast(bfrag, *(const u32x4*)&sEx[P][grp][0][lane][0]);
            hB[grp][1] = __builtin_bit_cast(bfrag, *(const u32x4*)&sEx[P][grp][1][lane][0]);
        }
        // out-projection: rotating wave handles both groups this step
        if ((t & 3) == q) {
            const bfrag wo0 = __builtin_bit_cast(bfrag, sWo[0][lane]);
            const bfrag wo1 = __builtin_bit_cast(bfrag, sWo[1][lane]);
#pragma unroll
            for (int grp = 0; grp < 2; ++grp) {
                f32x4 aO = obv;
                aO = MFMA16(wo0, hB[grp][0], aO);
                aO = MFMA16(wo1, hB[grp][1], aO);
                if (g < 2) {
                    float4 o; o.x = aO[0]; o.y = aO[1]; o.z = aO[2]; o.w = aO[3];
                    *(float4*)((char*)out + ooff + offg[grp]) = o;
                }
            }
        }
        ooff += istep;
    };
#pragma unroll 1
    for (int t = 0; t < T_STEPS; t += 2) {
        dec_body(0, t);
        dec_body(1, t + 1);
    }
}

extern "C" void kernel_launch(void* const* d_in, const int* in_sizes, int n_in,
                              void* d_out, int out_size, void* d_ws, size_t ws_size,
                              hipStream_t stream) {
    (void)in_sizes; (void)n_in; (void)d_ws; (void)ws_size; (void)out_size;
    const float* inputs = (const float*)d_in[0];
    const float* target = (const float*)d_in[1];
    const float* eWih   = (const float*)d_in[2];
    const float* eWhh   = (const float*)d_in[3];
    const float* ebih   = (const float*)d_in[4];
    const float* ebhh   = (const float*)d_in[5];
    const float* dWih   = (const float*)d_in[6];
    const float* dWhh   = (const float*)d_in[7];
    const float* dbih   = (const float*)d_in[8];
    const float* dbhh   = (const float*)d_in[9];
    const float* oW     = (const float*)d_in[10];
    const float* ob     = (const float*)d_in[11];
    float* out = (float*)d_out;

    seq2seq_r11_kernel<<<dim3(GRID_BLOCKS), dim3(BLOCK_THREADS), 0, stream>>>(
        inputs, target, eWih, eWhh, ebih, ebhh, dWih, dWhh, dbih, dbhh, oW, ob, out);
}